// Round 14
// baseline (625.125 us; speedup 1.0000x reference)
//
#include <hip/hip_runtime.h>
#include <cstdio>
#include <cstdint>

using u16 = unsigned short;
typedef __bf16 bf16x8 __attribute__((ext_vector_type(8)));
typedef float f32x4 __attribute__((ext_vector_type(4)));

#define GLOBAL_AS __attribute__((address_space(1)))
#define LDS_AS __attribute__((address_space(3)))

__device__ __forceinline__ float bf2f(u16 h) {
  return __uint_as_float(((unsigned)h) << 16);
}
__device__ __forceinline__ u16 f2bf(float f) {
  unsigned u = __float_as_uint(f);
  u += 0x7FFFu + ((u >> 16) & 1u);
  return (u16)(u >> 16);
}

__device__ __forceinline__ void async_copy16(void* lds, const void* g) {
  __builtin_amdgcn_global_load_lds((const GLOBAL_AS unsigned int*)g,
                                   (LDS_AS unsigned int*)lds, 16, 0, 0);
}

// ---------------- block reduction helper (blockDim = 256) ----------------
__device__ __forceinline__ float block_sum(float v, float* red) {
#pragma unroll
  for (int o = 32; o >= 1; o >>= 1) v += __shfl_xor(v, o);
  __syncthreads();
  if ((threadIdx.x & 63) == 0) red[threadIdx.x >> 6] = v;
  __syncthreads();
  return red[0] + red[1] + red[2] + red[3];
}

// ---------------- block reduction for blockDim = 1024 (16 waves) ----------------
__device__ __forceinline__ float block_sum16(float v, float* red) {
#pragma unroll
  for (int o = 32; o >= 1; o >>= 1) v += __shfl_xor(v, o);
  __syncthreads();  // protect red from previous reduction's readers
  if ((threadIdx.x & 63) == 0) red[threadIdx.x >> 6] = v;
  __syncthreads();
  float s = 0.f;
#pragma unroll
  for (int i = 0; i < 16; ++i) s += red[i];
  return s;
}

// ---------------- merged f32 -> bf16 converts (4 ranges, 1 launch) ----------------
__global__ __launch_bounds__(256) void cvt4_kernel(
    const float* __restrict__ s0, u16* __restrict__ d0,
    const float* __restrict__ s1, u16* __restrict__ d1,
    const float* __restrict__ s2, u16* __restrict__ d2,
    const float* __restrict__ s3, u16* __restrict__ d3) {
  const float* s; u16* d; long n; long b0; long nb;
  const int b = blockIdx.x;
  if (b < 2048)      { s = s0; d = d0; n = 37748736L; b0 = b;        nb = 2048; }
  else if (b < 2816) { s = s1; d = d1; n = 3145728L;  b0 = b - 2048; nb = 768; }
  else if (b < 3072) { s = s2; d = d2; n = 1048576L;  b0 = b - 2816; nb = 256; }
  else               { s = s3; d = d3; n = 143360L;   b0 = b - 3072; nb = 35; }
  long i = (b0 * 256 + threadIdx.x) * 4;
  const long stride = nb * 1024;
  for (; i < n; i += stride) {
    float4 v = *(const float4*)(s + i);
    ushort4 o;
    o.x = f2bf(v.x); o.y = f2bf(v.y); o.z = f2bf(v.z); o.w = f2bf(v.w);
    *(ushort4*)(d + i) = o;
  }
}

// =================================================================================
// Fused K+V+Q projection GEMM — 256x256 8-wave 4-phase schedule (round-6 proven).
// =================================================================================
template <int VTD>
__global__ __launch_bounds__(512, 2) void gemm_kvq_kernel(
    const u16* __restrict__ A, const u16* __restrict__ Bkv,
    const u16* __restrict__ Aq, const u16* __restrict__ Bq,
    u16* __restrict__ Ck, u16* __restrict__ Cvp, u16* __restrict__ Vt,
    u16* __restrict__ Cq,
    const float* __restrict__ bias, const float* __restrict__ biasq) {
  __shared__ char smem[131072];  // dbuf d: A at d*65536, B at d*65536+32768
  const int bid = blockIdx.x;
  const int t = threadIdx.x;
  const int wid = t >> 6, l = t & 63;
  const int wm = wid >> 2, wn = wid & 3;
  const int lr = l & 15, lg = l >> 4, lr7 = lr & 7;

  int mt = 0, nt = 0, qb = -1;
  const u16* Abase; const u16* Bbase; const float* bias_b;
  if (bid < 1152) {
    const int wgid = (bid & 7) * 144 + (bid >> 3);  // XCD swizzle (1152 = 8*144)
    mt = wgid >> 3; nt = wgid & 7;                  // nt fastest: A-panel L2 reuse
    Abase = A + (size_t)mt * 256 * 1024;
    Bbase = Bkv + (size_t)nt * 256 * 1024;
    bias_b = bias + nt * 256;
  } else {
    qb = bid - 1152;  // 0..3
    Abase = Aq;
    Bbase = Bq + (size_t)qb * 256 * 1024;
    bias_b = biasq + qb * 256;
  }

  const int srow = t >> 3;
  const int scx = (t & 7) ^ (srow & 7);
  const char* Asrc = (const char*)Abase + (size_t)srow * 2048 + (scx << 4);
  const char* Bsrc = (const char*)Bbase + (size_t)srow * 2048 + (scx << 4);
  const int wb = wid << 10;

  f32x4 acc[8][4] = {};

#define SA(d, r, kt) async_copy16(smem + (d)*65536 + (r)*8192 + wb, \
                                  Asrc + (size_t)(r)*131072 + (size_t)(kt)*128)
#define SB(d, r, kt) async_copy16(smem + (d)*65536 + 32768 + (r)*8192 + wb, \
                                  Bsrc + (size_t)(r)*131072 + (size_t)(kt)*128)

#define RA(d, half)                                                          \
  _Pragma("unroll")                                                          \
  for (int i = 0; i < 4; ++i) {                                              \
    const int row = wm * 128 + ((half)*4 + i) * 16 + lr;                     \
    af[i][0] = *(const bf16x8*)(smem + (d)*65536 + (row << 7) + ((lg ^ lr7) << 4));       \
    af[i][1] = *(const bf16x8*)(smem + (d)*65536 + (row << 7) + (((4 | lg) ^ lr7) << 4)); \
  }

#define RB(d, half)                                                          \
  _Pragma("unroll")                                                          \
  for (int j = 0; j < 2; ++j) {                                              \
    const int row = wn * 64 + ((half)*2 + j) * 16 + lr;                      \
    bfr[j][0] = *(const bf16x8*)(smem + (d)*65536 + 32768 + (row << 7) + ((lg ^ lr7) << 4));       \
    bfr[j][1] = *(const bf16x8*)(smem + (d)*65536 + 32768 + (row << 7) + (((4 | lg) ^ lr7) << 4)); \
  }

#define MM(mh, nh)                                                           \
  __builtin_amdgcn_s_setprio(1);                                             \
  _Pragma("unroll")                                                          \
  for (int ks = 0; ks < 2; ++ks)                                             \
    _Pragma("unroll")                                                        \
    for (int i = 0; i < 4; ++i)                                              \
      _Pragma("unroll")                                                      \
      for (int j = 0; j < 2; ++j)                                            \
        acc[(mh)*4 + i][(nh)*2 + j] = __builtin_amdgcn_mfma_f32_16x16x32_bf16( \
            af[i][ks], bfr[j][ks], acc[(mh)*4 + i][(nh)*2 + j], 0, 0, 0);    \
  __builtin_amdgcn_s_setprio(0);

  SA(0, 0, 0); SA(0, 1, 0); SA(0, 2, 0); SA(0, 3, 0);
  SB(0, 0, 0); SB(0, 1, 0); SB(0, 2, 0); SB(0, 3, 0);
  SA(1, 0, 1); SA(1, 2, 1);
  asm volatile("s_waitcnt vmcnt(2)" ::: "memory");
  __builtin_amdgcn_s_barrier();
  asm volatile("" ::: "memory");

#pragma unroll 1
  for (int kt = 0; kt < 16; ++kt) {
    const int cur = kt & 1, nxt = cur ^ 1;
    const bool pf1 = (kt < 15), pf2 = (kt < 14);
    bf16x8 af[4][2], bfr[2][2];
    RA(cur, 0);
    RB(cur, 0);
    if (pf1) { SB(nxt, 0, kt + 1); SB(nxt, 1, kt + 1); }
    __builtin_amdgcn_s_barrier();
    asm volatile("s_waitcnt lgkmcnt(0)" ::: "memory");
    MM(0, 0);
    __builtin_amdgcn_s_barrier();
    RB(cur, 1);
    if (pf1) { SB(nxt, 2, kt + 1); SB(nxt, 3, kt + 1); }
    __builtin_amdgcn_s_barrier();
    asm volatile("s_waitcnt lgkmcnt(0)" ::: "memory");
    MM(0, 1);
    if (pf1) asm volatile("s_waitcnt vmcnt(6)" ::: "memory");
    __builtin_amdgcn_s_barrier();
    RA(cur, 1);
    if (pf1) { SA(nxt, 1, kt + 1); SA(nxt, 3, kt + 1); }
    __builtin_amdgcn_s_barrier();
    asm volatile("s_waitcnt lgkmcnt(0)" ::: "memory");
    MM(1, 1);
    __builtin_amdgcn_s_barrier();
    RB(cur, 0);
    if (pf2) { SA(cur, 0, kt + 2); SA(cur, 2, kt + 2); }
    __builtin_amdgcn_s_barrier();
    asm volatile("s_waitcnt lgkmcnt(0)" ::: "memory");
    MM(1, 0);
    if (pf2)      asm volatile("s_waitcnt vmcnt(4)" ::: "memory");
    else if (pf1) asm volatile("s_waitcnt vmcnt(0)" ::: "memory");
    __builtin_amdgcn_s_barrier();
  }
#undef SA
#undef SB
#undef RA
#undef RB
#undef MM

  // ---------------- epilogue ----------------
  if (VTD && qb < 0 && nt >= 4) {
    u16* T = (u16*)smem;
    const int vc2 = t >> 1, seg = t & 1;
    const int vglob = (nt - 4) * 256 + vc2;
    const int h2 = vglob >> 7, d2 = vglob & 127;
#pragma unroll 1
    for (int mh = 0; mh < 2; ++mh) {
      __syncthreads();
      if (wm == mh) {
#pragma unroll
        for (int ni = 0; ni < 4; ++ni) {
          const int vc = wn * 64 + ni * 16 + lr;
          const float bv = bias_b[vc];
#pragma unroll
          for (int mi = 0; mi < 8; ++mi) {
            const int ml = mi * 16 + lg * 4;
            ushort4 pk;
            pk.x = f2bf(acc[mi][ni][0] + bv);
            pk.y = f2bf(acc[mi][ni][1] + bv);
            pk.z = f2bf(acc[mi][ni][2] + bv);
            pk.w = f2bf(acc[mi][ni][3] + bv);
            *(ushort4*)(T + (size_t)vc * 136 + ml) = pk;
          }
        }
      }
      __syncthreads();
      const int mg0 = mt * 256 + mh * 128 + seg * 64;
      const int bb = (unsigned)mg0 / 576u;
      const int k0 = mg0 - bb * 576;
      u16* dst = Vt + ((size_t)(bb * 8 + h2) * 128 + d2) * 576 + k0;
      const u16* src = T + (size_t)vc2 * 136 + seg * 64;
#pragma unroll
      for (int i2 = 0; i2 < 8; ++i2)
        *(uint4*)(dst + i2 * 8) = *(const uint4*)(src + i2 * 8);
    }
  } else {
    u16* D; int cb0;
    if (qb >= 0)      { D = Cq;  cb0 = qb * 256; }
    else if (nt < 4)  { D = Ck;  cb0 = nt * 256; }
    else              { D = Cvp; cb0 = (nt - 4) * 256; }
#pragma unroll
    for (int ni = 0; ni < 4; ++ni) {
      const int nc = wn * 64 + ni * 16 + lr;
      const float bv = bias_b[nc];
      const int col = cb0 + nc;
#pragma unroll
      for (int mi = 0; mi < 8; ++mi) {
#pragma unroll
        for (int rg = 0; rg < 4; ++rg) {
          const size_t m = (size_t)mt * 256 + wm * 128 + mi * 16 + lg * 4 + rg;
          D[m * 1024 + col] = f2bf(acc[mi][ni][rg] + bv);
        }
      }
    }
  }
}

// =================================================================================
// Generic deep-pipelined batched GEMM (round-2 proven loop; S + split-K out-proj)
// =================================================================================
template <int OUTF32>
__global__ __launch_bounds__(512, 2) void gemm_big_kernel(
    const u16* __restrict__ A, const u16* __restrict__ B, void* __restrict__ Cv,
    const float* __restrict__ bias, float scale,
    int KT, int ntx, int Mlim, int Nlim,
    long lda, long ldb, long ldc, int bdiv,
    long sA0, long sA1, long sB0, long sB1, long sC0, long sC1) {
  __shared__ u16 lds[3][24576];
  const int bid = blockIdx.x;
  const int bh = blockIdx.y;
  const int bb0 = bh / bdiv, bb1 = bh % bdiv;
  const int mt = bid / ntx, nt = bid % ntx;
  const int t = threadIdx.x;
  const int wid = t >> 6, l = t & 63;
  const int wr = wid >> 1, wc = wid & 1;
  const int lr = l & 15, lg = l >> 4, lr7 = lr & 7;

  const long ldab = lda * 2, ldbb = ldb * 2;
  const u16* Abase = A + (long)bb0 * sA0 + (long)bb1 * sA1 + (long)mt * 256 * lda;
  const u16* Bbase = B + (long)bb0 * sB0 + (long)bb1 * sB1 + (long)nt * 128 * ldb;

  const int srow = t >> 3;
  const int scx = (t & 7) ^ (srow & 7);
  const char* Asrc = (const char*)Abase + (long)srow * ldab + (scx << 4);
  const char* Bsrc = (const char*)Bbase + (long)srow * ldbb + (scx << 4);
  const int wbA = wid << 10;

  char* b0 = (char*)lds[0];
  char* b1 = (char*)lds[1];
  char* b2 = (char*)lds[2];

  f32x4 acc[4][4] = {};

#define STAGE3G(dst, kt, part)                                              \
  {                                                                         \
    const long ko = (long)(kt) * 128;                                       \
    if ((part) == 0) {                                                      \
      async_copy16((dst) + wbA,          Asrc + ko);                        \
      async_copy16((dst) + 8192 + wbA,   Asrc + 64 * ldab + ko);            \
      async_copy16((dst) + 16384 + wbA,  Asrc + 128 * ldab + ko);           \
    } else {                                                                \
      async_copy16((dst) + 24576 + wbA,  Asrc + 192 * ldab + ko);           \
      async_copy16((dst) + 32768 + wbA,  Bsrc + ko);                        \
      async_copy16((dst) + 40960 + wbA,  Bsrc + 64 * ldbb + ko);            \
    }                                                                       \
  }

#define COMPUTE_KS(p, KS)                                                   \
  {                                                                         \
    const int ccol = (((KS) << 2) | lg) ^ lr7;                              \
    const char* pA = (p) + (((wr << 6) + lr) << 7) + (ccol << 4);           \
    const char* pB = (p) + 32768 + (((wc << 6) + lr) << 7) + (ccol << 4);   \
    bf16x8 af[4], bfr[4];                                                   \
    _Pragma("unroll")                                                       \
    for (int i = 0; i < 4; ++i) {                                           \
      af[i]  = *(const bf16x8*)(pA + i * 2048);                             \
      bfr[i] = *(const bf16x8*)(pB + i * 2048);                             \
    }                                                                       \
    __builtin_amdgcn_s_setprio(1);                                          \
    _Pragma("unroll")                                                       \
    for (int mi = 0; mi < 4; ++mi)                                          \
      _Pragma("unroll")                                                     \
      for (int ni = 0; ni < 4; ++ni)                                        \
        acc[mi][ni] = __builtin_amdgcn_mfma_f32_16x16x32_bf16(              \
            af[mi], bfr[ni], acc[mi][ni], 0, 0, 0);                         \
    __builtin_amdgcn_s_setprio(0);                                          \
  }

  STAGE3G(b0, 0, 0); STAGE3G(b0, 0, 1);
  STAGE3G(b1, 1, 0); STAGE3G(b1, 1, 1);
  asm volatile("s_waitcnt vmcnt(6)" ::: "memory");
  __builtin_amdgcn_s_barrier();
  asm volatile("" ::: "memory");

  char* p0 = b0; char* p1 = b1; char* p2 = b2;
#pragma unroll 1
  for (int kt = 0; kt < KT; ++kt) {
    const bool pf = (kt < KT - 2);
    if (pf) STAGE3G(p2, kt + 2, 0);
    COMPUTE_KS(p0, 0);
    if (pf) STAGE3G(p2, kt + 2, 1);
    COMPUTE_KS(p0, 1);
    if (kt < KT - 1) {
      if (pf) asm volatile("s_waitcnt vmcnt(6)" ::: "memory");
      else    asm volatile("s_waitcnt vmcnt(0)" ::: "memory");
      __builtin_amdgcn_s_barrier();
      asm volatile("" ::: "memory");
    }
    char* tmp = p0; p0 = p1; p1 = p2; p2 = tmp;
  }
#undef STAGE3G
#undef COMPUTE_KS

  const long cBase = (long)bb0 * sC0 + (long)bb1 * sC1;
  const int mr0 = mt * 256 + wr * 64 + lg * 4;
  const int nc0 = nt * 128 + wc * 64 + lr;
#pragma unroll
  for (int ni = 0; ni < 4; ++ni) {
    const int n = nc0 + ni * 16;
    if (n >= Nlim) continue;
    const float bv = bias ? bias[n] : 0.0f;
#pragma unroll
    for (int mi = 0; mi < 4; ++mi) {
#pragma unroll
      for (int rg = 0; rg < 4; ++rg) {
        const int m = mr0 + mi * 16 + rg;
        if (m >= Mlim) continue;
        const float v = acc[mi][ni][rg] * scale + bv;
        if (OUTF32) ((float*)Cv)[cBase + (long)m * ldc + n] = v;
        else        ((u16*)Cv)[cBase + (long)m * ldc + n] = f2bf(v);
      }
    }
  }
}

// ---------------- V transpose (fallback path only) ----------------
__global__ __launch_bounds__(256) void transpose_v_kernel(const u16* __restrict__ V,
                                                          u16* __restrict__ Vt) {
  __shared__ u16 tile[64][65];
  const int k0 = blockIdx.x * 64;
  const int c0 = blockIdx.y * 64;
  const int b = blockIdx.z;
  const int t = threadIdx.x;
  const int tx = t & 15, ty = t >> 4;
  const u16* Vb = V + (size_t)(b * 576) * 1024;
#pragma unroll
  for (int i = 0; i < 4; ++i) {
    const int k = ty + i * 16;
    const u16* src = Vb + (size_t)(k0 + k) * 1024 + c0 + tx * 4;
    ushort2 v01 = *(const ushort2*)src;
    ushort2 v23 = *(const ushort2*)(src + 2);
    tile[k][tx * 4 + 0] = v01.x; tile[k][tx * 4 + 1] = v01.y;
    tile[k][tx * 4 + 2] = v23.x; tile[k][tx * 4 + 3] = v23.y;
  }
  __syncthreads();
  const int h = c0 >> 7, d0 = c0 & 127;
  u16* VtB = Vt + ((size_t)(b * 8 + h) * 128 + d0) * 576 + k0;
#pragma unroll
  for (int i = 0; i < 4; ++i) {
    const int d = ty + i * 16;
    u16* dst = VtB + (size_t)d * 576 + tx * 4;
    ushort2 a, bb2;
    a.x = tile[tx * 4 + 0][d]; a.y = tile[tx * 4 + 1][d];
    bb2.x = tile[tx * 4 + 2][d]; bb2.y = tile[tx * 4 + 3][d];
    *(ushort2*)dst = a; *(ushort2*)(dst + 2) = bb2;
  }
}

// =================================================================================
// softmax_pm (round-10 proven): softmax over k=576 per (b,h,q) row, no P write-back.
// =================================================================================
__global__ __launch_bounds__(512) void softmax_pm_kernel(const u16* __restrict__ SP,
                                                         float* __restrict__ attnOut,
                                                         u16* __restrict__ Pm) {
  const int b = blockIdx.x, c = blockIdx.y;
  const int h = threadIdx.x >> 6, l = threadIdx.x & 63;
  __shared__ float pl[8][576];  // 18.4 KB
  float pacc[9] = {};
#pragma unroll 1
  for (int qq = 0; qq < 10; ++qq) {
    const u16* row = SP + ((size_t)((b * 8 + h) * 144 + c * 10 + qq)) * 576;
    float x[9];
#pragma unroll
    for (int i = 0; i < 9; ++i) x[i] = bf2f(row[l + 64 * i]);
    float m = x[0];
#pragma unroll
    for (int i = 1; i < 9; ++i) m = fmaxf(m, x[i]);
#pragma unroll
    for (int o = 32; o >= 1; o >>= 1) m = fmaxf(m, __shfl_xor(m, o));
    float e[9], s = 0.f;
#pragma unroll
    for (int i = 0; i < 9; ++i) { e[i] = expf(x[i] - m); s += e[i]; }
#pragma unroll
    for (int o = 32; o >= 1; o >>= 1) s += __shfl_xor(s, o);
    const float inv = 1.f / s;
#pragma unroll
    for (int i = 0; i < 9; ++i) {
      const float p = e[i] * inv;
      pacc[i] += p;
      pl[h][l + 64 * i] = p;
    }
    __syncthreads();
    float* out = attnOut + ((size_t)(b * 140 + c * 10 + qq)) * 576;
    {
      const int j = threadIdx.x;
      float a = 0.f;
#pragma unroll
      for (int hh = 0; hh < 8; ++hh) a += pl[hh][j];
      out[j] = a * 0.125f;
      if (j < 64) {
        float a2 = 0.f;
#pragma unroll
        for (int hh = 0; hh < 8; ++hh) a2 += pl[hh][j + 512];
        out[j + 512] = a2 * 0.125f;
      }
    }
    __syncthreads();  // pl reused next qq
  }
  u16* pm = Pm + ((size_t)((b * 8 + h) * 14 + c)) * 576;
#pragma unroll
  for (int i = 0; i < 9; ++i) pm[l + 64 * i] = f2bf(pacc[i] * 0.1f);
}

// =================================================================================
// pv_small v2: one head per block, grid (64,8), 256 thr = 4 waves.
// =================================================================================
__global__ __launch_bounds__(256) void pv_small_kernel(const u16* __restrict__ Pm,
                                                       const u16* __restrict__ Vt,
                                                       u16* __restrict__ Attd) {
  const int b = blockIdx.x, h = blockIdx.y;
  const int t = threadIdx.x;
  const int w = t >> 6, l = t & 63;
  const int lr = l & 15, lg = l >> 4;
  __shared__ u16 pm[16][584];  // rows 14,15 + chunk 72 zeroed
  for (int i = t; i < 16 * 73; i += 256) {
    const int r = i / 73, ck = i - (i / 73) * 73;
    uint4 v = {0u, 0u, 0u, 0u};
    if (r < 14 && ck < 72)
      v = *(const uint4*)&Pm[((size_t)((b * 8 + h) * 14 + r)) * 576 + ck * 8];
    *(uint4*)&pm[r][ck * 8] = v;
  }
  __syncthreads();
  const u16* vbase = Vt + ((size_t)(b * 8 + h) * 128) * 576;
  f32x4 acc[2] = {};
#pragma unroll 1
  for (int ks = 0; ks < 18; ++ks) {
    const bf16x8 af = *(const bf16x8*)&pm[lr][ks * 32 + lg * 8];
#pragma unroll
    for (int j = 0; j < 2; ++j) {
      const int nf = w * 2 + j;
      const bf16x8 bf = *(const bf16x8*)&vbase[(size_t)(nf * 16 + lr) * 576 + ks * 32 + lg * 8];
      acc[j] = __builtin_amdgcn_mfma_f32_16x16x32_bf16(af, bf, acc[j], 0, 0, 0);
    }
  }
#pragma unroll
  for (int j = 0; j < 2; ++j) {
    const int nf = w * 2 + j;
#pragma unroll
    for (int rg = 0; rg < 4; ++rg) {
      const int cc = lg * 4 + rg;
      if (cc < 14)
        Attd[((size_t)b * 14 + cc) * 1024 + h * 128 + nf * 16 + lr] = f2bf(acc[j][rg]);
    }
  }
}

// ---------------- LN + per-class linear row (sums 4 split-K partials + bias) ----------------
__global__ __launch_bounds__(256) void ln_crossfc_kernel(
    const float* __restrict__ ap, long pstride, const float* __restrict__ outb,
    const float* __restrict__ g, const float* __restrict__ bb,
    const float* __restrict__ fw, const float* __restrict__ fb, float* __restrict__ out) {
  const int bc = blockIdx.x;
  const int c = bc % 14;
  const float* x = ap + (size_t)bc * 1024;
  __shared__ float red[4];
  const int t = threadIdx.x;
  float v[4];
  float s = 0.f;
#pragma unroll
  for (int i = 0; i < 4; ++i) {
    const int e = t + i * 256;
    v[i] = ((x[e] + x[e + pstride]) + x[e + 2 * pstride]) + x[e + 3 * pstride] + outb[e];
    s += v[i];
  }
  const float mean = block_sum(s, red) * (1.f / 1024.f);
  float vs = 0.f;
#pragma unroll
  for (int i = 0; i < 4; ++i) { const float d = v[i] - mean; vs += d * d; }
  const float var = block_sum(vs, red) * (1.f / 1024.f);
  const float inv = rsqrtf(var + 1e-5f);
  float acc = 0.f;
#pragma unroll
  for (int i = 0; i < 4; ++i) {
    const int e = t + i * 256;
    const float h = (v[i] - mean) * inv * g[e] + bb[e];
    acc += h * fw[(size_t)c * 1024 + e];
  }
  acc = block_sum(acc, red);
  if (t == 0) out[bc] = acc + fb[c];
}

// =================================================================================
// direct MLP v3 (round-13 proven): grid (64,4), 256 thr, partials to Lpart.
// =================================================================================
__global__ __launch_bounds__(256) void direct_mlp_kernel(
    const float* __restrict__ vg, const float* __restrict__ g, const float* __restrict__ bb,
    const float* __restrict__ w1, const float* __restrict__ b1,
    const float* __restrict__ w2, float* __restrict__ Lpart) {
  const int b = blockIdx.x, q = blockIdx.y;
  __shared__ float red[4];
  __shared__ float gn[1024];
  __shared__ float h1[128];
  const int t = threadIdx.x;
  const float* x = vg + (size_t)b * 1024;
  float v[4];
  float s = 0.f;
#pragma unroll
  for (int i = 0; i < 4; ++i) { v[i] = x[t + i * 256]; s += v[i]; }
  const float mean = block_sum(s, red) * (1.f / 1024.f);
  float vs = 0.f;
#pragma unroll
  for (int i = 0; i < 4; ++i) { const float d = v[i] - mean; vs += d * d; }
  const float var = block_sum(vs, red) * (1.f / 1024.f);
  const float inv = rsqrtf(var + 1e-5f);
#pragma unroll
  for (int i = 0; i < 4; ++i) {
    const int e = t + i * 256;
    gn[e] = (v[i] - mean) * inv * g[e] + bb[e];
  }
  __syncthreads();
  {
    const int row = q * 128 + (t >> 1);  // 2 threads per row
    const int half = t & 1;
    const float4* wr = (const float4*)(w1 + (size_t)row * 1024 + half * 512);
    const float4* g4 = (const float4*)(gn + half * 512);
    float a = 0.f;
    for (int e = 0; e < 128; ++e) {
      const float4 wv = wr[e], av = g4[e];
      a += av.x * wv.x + av.y * wv.y + av.z * wv.z + av.w * wv.w;
    }
    a += __shfl_xor(a, 1);  // pair lanes (2r, 2r+1)
    if (half == 0) h1[t >> 1] = fmaxf(a + b1[row], 0.f);
  }
  __syncthreads();
  for (int c = 0; c < 14; ++c) {
    float a = 0.f;
    if (t < 128) a = h1[t] * w2[(size_t)c * 512 + q * 128 + t];
    a = block_sum(a, red);
    if (t == 0) Lpart[((size_t)b * 4 + q) * 14 + c] = a;
  }
}

// ---------------- small f32 linear (round-7 proven: 1 row/block, grid (64,4)) ----------------
__global__ __launch_bounds__(256) void linear_f32_kernel(
    const float* __restrict__ A, const float* __restrict__ W, const float* __restrict__ bias,
    float* __restrict__ C, int N, int Kd) {
  const int r = blockIdx.x;
  const int j = blockIdx.y * 256 + threadIdx.x;
  __shared__ float a[1024];
  for (int e = threadIdx.x; e < Kd; e += 256) a[e] = A[(size_t)r * Kd + e];
  __syncthreads();
  float acc = bias ? bias[j] : 0.f;
  const float4* wr = (const float4*)(W + (size_t)j * Kd);
  const float4* a4 = (const float4*)a;
  for (int e = 0; e < Kd / 4; ++e) {
    float4 wv = wr[e], av = a4[e];
    acc += av.x * wv.x + av.y * wv.y + av.z * wv.z + av.w * wv.w;
  }
  C[(size_t)r * N + j] = acc;
}

// =================================================================================
// sim3: linear3 (Co row) + cosine sim + combine, one 1024-thread block per b.
// Thread j computes Co[j] = Cv2[b,:].Wco[j,:] + bco[j] (same order as linear_f32),
// then block-reduces dd/nc/nt over 1024 lanes; t<14 writes the three logit rows.
// =================================================================================
__global__ __launch_bounds__(1024) void sim3_kernel(
    const float* __restrict__ Cv2, const float* __restrict__ Wco,
    const float* __restrict__ bco, const float* __restrict__ tp,
    const float* __restrict__ lc, const float* __restrict__ Lpart,
    const float* __restrict__ b2, float* __restrict__ out) {
  const int b = blockIdx.x;
  const int t = threadIdx.x;
  __shared__ float a[1024];
  __shared__ float red[16];
  a[t] = Cv2[(size_t)b * 1024 + t];
  __syncthreads();
  float acc = bco[t];
  const float4* wr = (const float4*)(Wco + (size_t)t * 1024);
  const float4* a4 = (const float4*)a;
  for (int e = 0; e < 256; ++e) {
    const float4 wv = wr[e], av = a4[e];
    acc += av.x * wv.x + av.y * wv.y + av.z * wv.z + av.w * wv.w;
  }
  const float pv = tp[(size_t)b * 1024 + t];
  const float dd = block_sum16(acc * pv, red);
  const float nc = block_sum16(acc * acc, red);
  const float nt = block_sum16(pv * pv, red);
  const float sim = dd / (fmaxf(sqrtf(nc), 1e-12f) * fmaxf(sqrtf(nt), 1e-12f)) / 0.1f;
  if (t < 14) {
    const int i = b * 14 + t;
    const float ld = ((Lpart[((size_t)b * 4 + 0) * 14 + t] +
                       Lpart[((size_t)b * 4 + 1) * 14 + t]) +
                      Lpart[((size_t)b * 4 + 2) * 14 + t]) +
                     Lpart[((size_t)b * 4 + 3) * 14 + t] + b2[t];
    const float sup = 0.5f * (lc[i] + ld);
    out[i] = sim;
    out[896 + i] = sup;
    out[1792 + i] = 0.5f * (sup + sim);
  }
}

// ---------------- workspace layout ----------------
static constexpr size_t OFF_X    = 0;
static constexpr size_t OFF_K    = OFF_X + 75497472;   // Kb; later Pm (8.3MB)
static constexpr size_t OFF_SP   = OFF_K + 75759616;   // V-fallback / S / Aprj4 (14.7MB)
static constexpr size_t OFF_WIN  = OFF_SP + 85082112;
static constexpr size_t OFF_WOUT = OFF_WIN + 6291456;
static constexpr size_t OFF_ASP  = OFF_WOUT + 2097152; // Asp; later Lpart (14KB)
static constexpr size_t OFF_QASP = OFF_ASP + 524288;
static constexpr size_t OFF_ATT  = OFF_QASP + 524288;
static constexpr size_t OFF_APRJ = OFF_ATT + 1835008;  // (unused this round)
static constexpr size_t OFF_TP   = OFF_APRJ + 3670016;
static constexpr size_t OFF_CV   = OFF_TP + 262144;
static constexpr size_t OFF_CO   = OFF_CV + 262144;
static constexpr size_t OFF_SIM  = OFF_CO + 262144;
static constexpr size_t OFF_LC   = OFF_SIM + 4096;
static constexpr size_t OFF_LD   = OFF_LC + 4096;
static constexpr size_t WS_SMALL = OFF_LD + 4096;
static constexpr size_t OFF_VT   = WS_SMALL;
static constexpr size_t WS_BIG   = OFF_VT + 75497472;

extern "C" void kernel_launch(void* const* d_in, const int* in_sizes, int n_in,
                              void* d_out, int out_size, void* d_ws, size_t ws_size,
                              hipStream_t stream) {
  (void)in_sizes; (void)n_in; (void)out_size;
  const float* vision_features = (const float*)d_in[0];
  const float* text_embeddings = (const float*)d_in[1];
  const float* vision_global   = (const float*)d_in[2];
  const float* aspect_queries  = (const float*)d_in[3];
  const float* ch_in_w  = (const float*)d_in[4];
  const float* ch_in_b  = (const float*)d_in[5];
  const float* ch_out_w = (const float*)d_in[6];
  const float* ch_out_b = (const float*)d_in[7];
  const float* tp_w = (const float*)d_in[8];
  const float* tp_b = (const float*)d_in[9];
  const float* ca_in_w  = (const float*)d_in[10];
  const float* ca_in_b  = (const float*)d_in[11];
  const float* ca_out_w = (const float*)d_in[12];
  const float* ca_out_b = (const float*)d_in[13];
  const float* cross_ln_g = (const float*)d_in[14];
  const float* cross_ln_b = (const float*)d_in[15];
  const float* cross_fc_w = (const float*)d_in[16];
  const float* cross_fc_b = (const float*)d_in[17];
  const float* dir_ln_g = (const float*)d_in[18];
  const float* dir_ln_b = (const float*)d_in[19];
  const float* dir_w1 = (const float*)d_in[20];
  const float* dir_b1 = (const float*)d_in[21];
  const float* dir_w2 = (const float*)d_in[22];
  const float* dir_b2 = (const float*)d_in[23];

  if (ws_size < WS_SMALL) {
    fprintf(stderr, "kernel_launch: ws too small: %zu < %zu\n", ws_size, WS_SMALL);
    return;
  }
  const bool big = (ws_size >= WS_BIG);

  char* ws = (char*)d_ws;
  u16* Xb      = (u16*)(ws + OFF_X);
  u16* Kb      = (u16*)(ws + OFF_K);
  u16* Pm      = (u16*)(ws + OFF_K);    // after S-GEMM, Kb is dead
  u16* Vb      = (u16*)(ws + OFF_SP);
  u16* SP      = (u16*)(ws + OFF_SP);
  float* Aprj4 = (float*)(ws + OFF_SP); // after softmax, SP is dead (4 partials)
  u16* Vt      = big ? (u16*)(ws + OFF_VT) : (u16*)(ws + OFF_X);
  u16* Win     = (u16*)(ws + OFF_WIN);
  u16* Wout    = (u16*)(ws + OFF_WOUT);
  u16* Asp     = (u16*)(ws + OFF_ASP);
  float* Lpart = (float*)(ws + OFF_ASP);  // after KVQ, Asp is dead
  u16* Qasp    = (u16*)(ws + OFF_QASP);
  u16* Attd    = (u16*)(ws + OFF_ATT);
  float* Tp    = (float*)(ws + OFF_TP);
  float* Cv2   = (float*)(ws + OFF_CV);
  float* Lc    = (float*)(ws + OFF_LC);
  float* attnOut = (float*)d_out + 2688;

  // ---- converts to bf16 ----
  cvt4_kernel<<<3107, 256, 0, stream>>>(vision_features, Xb, ca_in_w, Win,
                                        ca_out_w, Wout, aspect_queries, Asp);

  // ---- fused K+V+Q projections, 256x256 4-phase pipeline ----
  if (big) {
    gemm_kvq_kernel<1><<<dim3(1156), 512, 0, stream>>>(
        Xb, Win + 1024 * 1024, Asp, Win, Kb, nullptr, Vt, Qasp,
        ca_in_b + 1024, ca_in_b);
  } else {
    gemm_kvq_kernel<0><<<dim3(1156), 512, 0, stream>>>(
        Xb, Win + 1024 * 1024, Asp, Win, Kb, Vb, nullptr, Qasp,
        ca_in_b + 1024, ca_in_b);
    transpose_v_kernel<<<dim3(9, 16, 64), 256, 0, stream>>>(Vb, Vt);
  }

  // ---- direct MLP v3 (Asp region now dead; writes Lpart there) ----
  direct_mlp_kernel<<<dim3(64, 4), 256, 0, stream>>>(
      vision_global, dir_ln_g, dir_ln_b, dir_w1, dir_b1, dir_w2, Lpart);

  // ---- S = Q K^T / sqrt(128): KT=2, grid (5 n-tiles, 512 bh), bf16 out ----
  gemm_big_kernel<0><<<dim3(5, 512), 512, 0, stream>>>(
      Qasp, Kb, SP, nullptr, 0.08838834764831845f,
      2, 5, 140, 576, 1024, 1024, 576, 8,
      0L, 128L, 589824L, 128L, 663552L, 82944L);

  // ---- softmax + head-mean attnOut + query-mean Pm ----
  softmax_pm_kernel<<<dim3(64, 14), 512, 0, stream>>>(SP, attnOut, Pm);

  // ---- attended = Pm . V  (pv_small v2) ----
  pv_small_kernel<<<dim3(64, 8), 256, 0, stream>>>(Pm, Vt, Attd);

  // ---- contrastive chain first two hops (independent of out-proj) ----
  linear_f32_kernel<<<dim3(64, 4), 256, 0, stream>>>(text_embeddings, tp_w, tp_b, Tp, 1024, 1024);
  linear_f32_kernel<<<dim3(64, 4), 256, 0, stream>>>(Tp, ch_in_w + 2048 * 1024, ch_in_b + 2048, Cv2, 1024, 1024);

  // ---- out projection, split-K 4: grid (32 tiles, 4 splits), partials (no bias) ----
  // SP region is dead after softmax; Aprj4 = 4 x (896x1024) f32 partials.
  gemm_big_kernel<1><<<dim3(32, 4), 512, 0, stream>>>(
      Attd, Wout, Aprj4, nullptr, 1.0f,
      4, 8, 896, 1024, 1024, 1024, 1024, 1,
      256L, 0L, 256L, 0L, 917504L, 0L);

  // ---- LN + per-class fc (sums 4 partials + ca_out_b) ----
  ln_crossfc_kernel<<<896, 256, 0, stream>>>(Aprj4, 917504L, ca_out_b,
                                             cross_ln_g, cross_ln_b,
                                             cross_fc_w, cross_fc_b, Lc);

  // ---- linear3 + sim + combine (merged, 1024 thr/block) ----
  sim3_kernel<<<64, 1024, 0, stream>>>(Cv2, ch_out_w, ch_out_b, Tp, Lc, Lpart,
                                       dir_b2, (float*)d_out);
}

// Round 15
// 548.475 us; speedup vs baseline: 1.1398x; 1.1398x over previous
//
#include <hip/hip_runtime.h>
#include <cstdio>
#include <cstdint>

using u16 = unsigned short;
typedef __bf16 bf16x8 __attribute__((ext_vector_type(8)));
typedef float f32x4 __attribute__((ext_vector_type(4)));

#define GLOBAL_AS __attribute__((address_space(1)))
#define LDS_AS __attribute__((address_space(3)))

__device__ __forceinline__ float bf2f(u16 h) {
  return __uint_as_float(((unsigned)h) << 16);
}
__device__ __forceinline__ u16 f2bf(float f) {
  unsigned u = __float_as_uint(f);
  u += 0x7FFFu + ((u >> 16) & 1u);
  return (u16)(u >> 16);
}

__device__ __forceinline__ void async_copy16(void* lds, const void* g) {
  __builtin_amdgcn_global_load_lds((const GLOBAL_AS unsigned int*)g,
                                   (LDS_AS unsigned int*)lds, 16, 0, 0);
}

// ---------------- block reduction helper (blockDim = 256) ----------------
__device__ __forceinline__ float block_sum(float v, float* red) {
#pragma unroll
  for (int o = 32; o >= 1; o >>= 1) v += __shfl_xor(v, o);
  __syncthreads();
  if ((threadIdx.x & 63) == 0) red[threadIdx.x >> 6] = v;
  __syncthreads();
  return red[0] + red[1] + red[2] + red[3];
}

// ---------------- merged f32 -> bf16 converts (4 ranges, 1 launch) ----------------
__global__ __launch_bounds__(256) void cvt4_kernel(
    const float* __restrict__ s0, u16* __restrict__ d0,
    const float* __restrict__ s1, u16* __restrict__ d1,
    const float* __restrict__ s2, u16* __restrict__ d2,
    const float* __restrict__ s3, u16* __restrict__ d3) {
  const float* s; u16* d; long n; long b0; long nb;
  const int b = blockIdx.x;
  if (b < 2048)      { s = s0; d = d0; n = 37748736L; b0 = b;        nb = 2048; }
  else if (b < 2816) { s = s1; d = d1; n = 3145728L;  b0 = b - 2048; nb = 768; }
  else if (b < 3072) { s = s2; d = d2; n = 1048576L;  b0 = b - 2816; nb = 256; }
  else               { s = s3; d = d3; n = 143360L;   b0 = b - 3072; nb = 35; }
  long i = (b0 * 256 + threadIdx.x) * 4;
  const long stride = nb * 1024;
  for (; i < n; i += stride) {
    float4 v = *(const float4*)(s + i);
    ushort4 o;
    o.x = f2bf(v.x); o.y = f2bf(v.y); o.z = f2bf(v.z); o.w = f2bf(v.w);
    *(ushort4*)(d + i) = o;
  }
}

// =================================================================================
// Fused K+V+Q projection GEMM — 256x256 8-wave 4-phase schedule (round-6 proven).
// =================================================================================
template <int VTD>
__global__ __launch_bounds__(512, 2) void gemm_kvq_kernel(
    const u16* __restrict__ A, const u16* __restrict__ Bkv,
    const u16* __restrict__ Aq, const u16* __restrict__ Bq,
    u16* __restrict__ Ck, u16* __restrict__ Cvp, u16* __restrict__ Vt,
    u16* __restrict__ Cq,
    const float* __restrict__ bias, const float* __restrict__ biasq) {
  __shared__ char smem[131072];  // dbuf d: A at d*65536, B at d*65536+32768
  const int bid = blockIdx.x;
  const int t = threadIdx.x;
  const int wid = t >> 6, l = t & 63;
  const int wm = wid >> 2, wn = wid & 3;
  const int lr = l & 15, lg = l >> 4, lr7 = lr & 7;

  int mt = 0, nt = 0, qb = -1;
  const u16* Abase; const u16* Bbase; const float* bias_b;
  if (bid < 1152) {
    const int wgid = (bid & 7) * 144 + (bid >> 3);  // XCD swizzle (1152 = 8*144)
    mt = wgid >> 3; nt = wgid & 7;                  // nt fastest: A-panel L2 reuse
    Abase = A + (size_t)mt * 256 * 1024;
    Bbase = Bkv + (size_t)nt * 256 * 1024;
    bias_b = bias + nt * 256;
  } else {
    qb = bid - 1152;  // 0..3
    Abase = Aq;
    Bbase = Bq + (size_t)qb * 256 * 1024;
    bias_b = biasq + qb * 256;
  }

  const int srow = t >> 3;
  const int scx = (t & 7) ^ (srow & 7);
  const char* Asrc = (const char*)Abase + (size_t)srow * 2048 + (scx << 4);
  const char* Bsrc = (const char*)Bbase + (size_t)srow * 2048 + (scx << 4);
  const int wb = wid << 10;

  f32x4 acc[8][4] = {};

#define SA(d, r, kt) async_copy16(smem + (d)*65536 + (r)*8192 + wb, \
                                  Asrc + (size_t)(r)*131072 + (size_t)(kt)*128)
#define SB(d, r, kt) async_copy16(smem + (d)*65536 + 32768 + (r)*8192 + wb, \
                                  Bsrc + (size_t)(r)*131072 + (size_t)(kt)*128)

#define RA(d, half)                                                          \
  _Pragma("unroll")                                                          \
  for (int i = 0; i < 4; ++i) {                                              \
    const int row = wm * 128 + ((half)*4 + i) * 16 + lr;                     \
    af[i][0] = *(const bf16x8*)(smem + (d)*65536 + (row << 7) + ((lg ^ lr7) << 4));       \
    af[i][1] = *(const bf16x8*)(smem + (d)*65536 + (row << 7) + (((4 | lg) ^ lr7) << 4)); \
  }

#define RB(d, half)                                                          \
  _Pragma("unroll")                                                          \
  for (int j = 0; j < 2; ++j) {                                              \
    const int row = wn * 64 + ((half)*2 + j) * 16 + lr;                      \
    bfr[j][0] = *(const bf16x8*)(smem + (d)*65536 + 32768 + (row << 7) + ((lg ^ lr7) << 4));       \
    bfr[j][1] = *(const bf16x8*)(smem + (d)*65536 + 32768 + (row << 7) + (((4 | lg) ^ lr7) << 4)); \
  }

#define MM(mh, nh)                                                           \
  __builtin_amdgcn_s_setprio(1);                                             \
  _Pragma("unroll")                                                          \
  for (int ks = 0; ks < 2; ++ks)                                             \
    _Pragma("unroll")                                                        \
    for (int i = 0; i < 4; ++i)                                              \
      _Pragma("unroll")                                                      \
      for (int j = 0; j < 2; ++j)                                            \
        acc[(mh)*4 + i][(nh)*2 + j] = __builtin_amdgcn_mfma_f32_16x16x32_bf16( \
            af[i][ks], bfr[j][ks], acc[(mh)*4 + i][(nh)*2 + j], 0, 0, 0);    \
  __builtin_amdgcn_s_setprio(0);

  SA(0, 0, 0); SA(0, 1, 0); SA(0, 2, 0); SA(0, 3, 0);
  SB(0, 0, 0); SB(0, 1, 0); SB(0, 2, 0); SB(0, 3, 0);
  SA(1, 0, 1); SA(1, 2, 1);
  asm volatile("s_waitcnt vmcnt(2)" ::: "memory");
  __builtin_amdgcn_s_barrier();
  asm volatile("" ::: "memory");

#pragma unroll 1
  for (int kt = 0; kt < 16; ++kt) {
    const int cur = kt & 1, nxt = cur ^ 1;
    const bool pf1 = (kt < 15), pf2 = (kt < 14);
    bf16x8 af[4][2], bfr[2][2];
    RA(cur, 0);
    RB(cur, 0);
    if (pf1) { SB(nxt, 0, kt + 1); SB(nxt, 1, kt + 1); }
    __builtin_amdgcn_s_barrier();
    asm volatile("s_waitcnt lgkmcnt(0)" ::: "memory");
    MM(0, 0);
    __builtin_amdgcn_s_barrier();
    RB(cur, 1);
    if (pf1) { SB(nxt, 2, kt + 1); SB(nxt, 3, kt + 1); }
    __builtin_amdgcn_s_barrier();
    asm volatile("s_waitcnt lgkmcnt(0)" ::: "memory");
    MM(0, 1);
    if (pf1) asm volatile("s_waitcnt vmcnt(6)" ::: "memory");
    __builtin_amdgcn_s_barrier();
    RA(cur, 1);
    if (pf1) { SA(nxt, 1, kt + 1); SA(nxt, 3, kt + 1); }
    __builtin_amdgcn_s_barrier();
    asm volatile("s_waitcnt lgkmcnt(0)" ::: "memory");
    MM(1, 1);
    __builtin_amdgcn_s_barrier();
    RB(cur, 0);
    if (pf2) { SA(cur, 0, kt + 2); SA(cur, 2, kt + 2); }
    __builtin_amdgcn_s_barrier();
    asm volatile("s_waitcnt lgkmcnt(0)" ::: "memory");
    MM(1, 0);
    if (pf2)      asm volatile("s_waitcnt vmcnt(4)" ::: "memory");
    else if (pf1) asm volatile("s_waitcnt vmcnt(0)" ::: "memory");
    __builtin_amdgcn_s_barrier();
  }
#undef SA
#undef SB
#undef RA
#undef RB
#undef MM

  // ---------------- epilogue ----------------
  if (VTD && qb < 0 && nt >= 4) {
    u16* T = (u16*)smem;
    const int vc2 = t >> 1, seg = t & 1;
    const int vglob = (nt - 4) * 256 + vc2;
    const int h2 = vglob >> 7, d2 = vglob & 127;
#pragma unroll 1
    for (int mh = 0; mh < 2; ++mh) {
      __syncthreads();
      if (wm == mh) {
#pragma unroll
        for (int ni = 0; ni < 4; ++ni) {
          const int vc = wn * 64 + ni * 16 + lr;
          const float bv = bias_b[vc];
#pragma unroll
          for (int mi = 0; mi < 8; ++mi) {
            const int ml = mi * 16 + lg * 4;
            ushort4 pk;
            pk.x = f2bf(acc[mi][ni][0] + bv);
            pk.y = f2bf(acc[mi][ni][1] + bv);
            pk.z = f2bf(acc[mi][ni][2] + bv);
            pk.w = f2bf(acc[mi][ni][3] + bv);
            *(ushort4*)(T + (size_t)vc * 136 + ml) = pk;
          }
        }
      }
      __syncthreads();
      const int mg0 = mt * 256 + mh * 128 + seg * 64;
      const int bb = (unsigned)mg0 / 576u;
      const int k0 = mg0 - bb * 576;
      u16* dst = Vt + ((size_t)(bb * 8 + h2) * 128 + d2) * 576 + k0;
      const u16* src = T + (size_t)vc2 * 136 + seg * 64;
#pragma unroll
      for (int i2 = 0; i2 < 8; ++i2)
        *(uint4*)(dst + i2 * 8) = *(const uint4*)(src + i2 * 8);
    }
  } else {
    u16* D; int cb0;
    if (qb >= 0)      { D = Cq;  cb0 = qb * 256; }
    else if (nt < 4)  { D = Ck;  cb0 = nt * 256; }
    else              { D = Cvp; cb0 = (nt - 4) * 256; }
#pragma unroll
    for (int ni = 0; ni < 4; ++ni) {
      const int nc = wn * 64 + ni * 16 + lr;
      const float bv = bias_b[nc];
      const int col = cb0 + nc;
#pragma unroll
      for (int mi = 0; mi < 8; ++mi) {
#pragma unroll
        for (int rg = 0; rg < 4; ++rg) {
          const size_t m = (size_t)mt * 256 + wm * 128 + mi * 16 + lg * 4 + rg;
          D[m * 1024 + col] = f2bf(acc[mi][ni][rg] + bv);
        }
      }
    }
  }
}

// =================================================================================
// Generic deep-pipelined batched GEMM (round-2 proven loop; used for S, out-proj)
// =================================================================================
template <int OUTF32>
__global__ __launch_bounds__(512, 2) void gemm_big_kernel(
    const u16* __restrict__ A, const u16* __restrict__ B, void* __restrict__ Cv,
    const float* __restrict__ bias, float scale,
    int KT, int ntx, int Mlim, int Nlim,
    long lda, long ldb, long ldc, int bdiv,
    long sA0, long sA1, long sB0, long sB1, long sC0, long sC1) {
  __shared__ u16 lds[3][24576];
  const int bid = blockIdx.x;
  const int bh = blockIdx.y;
  const int bb0 = bh / bdiv, bb1 = bh % bdiv;
  const int mt = bid / ntx, nt = bid % ntx;
  const int t = threadIdx.x;
  const int wid = t >> 6, l = t & 63;
  const int wr = wid >> 1, wc = wid & 1;
  const int lr = l & 15, lg = l >> 4, lr7 = lr & 7;

  const long ldab = lda * 2, ldbb = ldb * 2;
  const u16* Abase = A + (long)bb0 * sA0 + (long)bb1 * sA1 + (long)mt * 256 * lda;
  const u16* Bbase = B + (long)bb0 * sB0 + (long)bb1 * sB1 + (long)nt * 128 * ldb;

  const int srow = t >> 3;
  const int scx = (t & 7) ^ (srow & 7);
  const char* Asrc = (const char*)Abase + (long)srow * ldab + (scx << 4);
  const char* Bsrc = (const char*)Bbase + (long)srow * ldbb + (scx << 4);
  const int wbA = wid << 10;

  char* b0 = (char*)lds[0];
  char* b1 = (char*)lds[1];
  char* b2 = (char*)lds[2];

  f32x4 acc[4][4] = {};

#define STAGE3G(dst, kt, part)                                              \
  {                                                                         \
    const long ko = (long)(kt) * 128;                                       \
    if ((part) == 0) {                                                      \
      async_copy16((dst) + wbA,          Asrc + ko);                        \
      async_copy16((dst) + 8192 + wbA,   Asrc + 64 * ldab + ko);            \
      async_copy16((dst) + 16384 + wbA,  Asrc + 128 * ldab + ko);           \
    } else {                                                                \
      async_copy16((dst) + 24576 + wbA,  Asrc + 192 * ldab + ko);           \
      async_copy16((dst) + 32768 + wbA,  Bsrc + ko);                        \
      async_copy16((dst) + 40960 + wbA,  Bsrc + 64 * ldbb + ko);            \
    }                                                                       \
  }

#define COMPUTE_KS(p, KS)                                                   \
  {                                                                         \
    const int ccol = (((KS) << 2) | lg) ^ lr7;                              \
    const char* pA = (p) + (((wr << 6) + lr) << 7) + (ccol << 4);           \
    const char* pB = (p) + 32768 + (((wc << 6) + lr) << 7) + (ccol << 4);   \
    bf16x8 af[4], bfr[4];                                                   \
    _Pragma("unroll")                                                       \
    for (int i = 0; i < 4; ++i) {                                           \
      af[i]  = *(const bf16x8*)(pA + i * 2048);                             \
      bfr[i] = *(const bf16x8*)(pB + i * 2048);                             \
    }                                                                       \
    __builtin_amdgcn_s_setprio(1);                                          \
    _Pragma("unroll")                                                       \
    for (int mi = 0; mi < 4; ++mi)                                          \
      _Pragma("unroll")                                                     \
      for (int ni = 0; ni < 4; ++ni)                                        \
        acc[mi][ni] = __builtin_amdgcn_mfma_f32_16x16x32_bf16(              \
            af[mi], bfr[ni], acc[mi][ni], 0, 0, 0);                         \
    __builtin_amdgcn_s_setprio(0);                                          \
  }

  STAGE3G(b0, 0, 0); STAGE3G(b0, 0, 1);
  STAGE3G(b1, 1, 0); STAGE3G(b1, 1, 1);
  asm volatile("s_waitcnt vmcnt(6)" ::: "memory");
  __builtin_amdgcn_s_barrier();
  asm volatile("" ::: "memory");

  char* p0 = b0; char* p1 = b1; char* p2 = b2;
#pragma unroll 1
  for (int kt = 0; kt < KT; ++kt) {
    const bool pf = (kt < KT - 2);
    if (pf) STAGE3G(p2, kt + 2, 0);
    COMPUTE_KS(p0, 0);
    if (pf) STAGE3G(p2, kt + 2, 1);
    COMPUTE_KS(p0, 1);
    if (kt < KT - 1) {
      if (pf) asm volatile("s_waitcnt vmcnt(6)" ::: "memory");
      else    asm volatile("s_waitcnt vmcnt(0)" ::: "memory");
      __builtin_amdgcn_s_barrier();
      asm volatile("" ::: "memory");
    }
    char* tmp = p0; p0 = p1; p1 = p2; p2 = tmp;
  }
#undef STAGE3G
#undef COMPUTE_KS

  const long cBase = (long)bb0 * sC0 + (long)bb1 * sC1;
  const int mr0 = mt * 256 + wr * 64 + lg * 4;
  const int nc0 = nt * 128 + wc * 64 + lr;
#pragma unroll
  for (int ni = 0; ni < 4; ++ni) {
    const int n = nc0 + ni * 16;
    if (n >= Nlim) continue;
    const float bv = bias ? bias[n] : 0.0f;
#pragma unroll
    for (int mi = 0; mi < 4; ++mi) {
#pragma unroll
      for (int rg = 0; rg < 4; ++rg) {
        const int m = mr0 + mi * 16 + rg;
        if (m >= Mlim) continue;
        const float v = acc[mi][ni][rg] * scale + bv;
        if (OUTF32) ((float*)Cv)[cBase + (long)m * ldc + n] = v;
        else        ((u16*)Cv)[cBase + (long)m * ldc + n] = f2bf(v);
      }
    }
  }
}

// ---------------- V transpose (fallback path only) ----------------
__global__ __launch_bounds__(256) void transpose_v_kernel(const u16* __restrict__ V,
                                                          u16* __restrict__ Vt) {
  __shared__ u16 tile[64][65];
  const int k0 = blockIdx.x * 64;
  const int c0 = blockIdx.y * 64;
  const int b = blockIdx.z;
  const int t = threadIdx.x;
  const int tx = t & 15, ty = t >> 4;
  const u16* Vb = V + (size_t)(b * 576) * 1024;
#pragma unroll
  for (int i = 0; i < 4; ++i) {
    const int k = ty + i * 16;
    const u16* src = Vb + (size_t)(k0 + k) * 1024 + c0 + tx * 4;
    ushort2 v01 = *(const ushort2*)src;
    ushort2 v23 = *(const ushort2*)(src + 2);
    tile[k][tx * 4 + 0] = v01.x; tile[k][tx * 4 + 1] = v01.y;
    tile[k][tx * 4 + 2] = v23.x; tile[k][tx * 4 + 3] = v23.y;
  }
  __syncthreads();
  const int h = c0 >> 7, d0 = c0 & 127;
  u16* VtB = Vt + ((size_t)(b * 8 + h) * 128 + d0) * 576 + k0;
#pragma unroll
  for (int i = 0; i < 4; ++i) {
    const int d = ty + i * 16;
    u16* dst = VtB + (size_t)d * 576 + tx * 4;
    ushort2 a, bb2;
    a.x = tile[tx * 4 + 0][d]; a.y = tile[tx * 4 + 1][d];
    bb2.x = tile[tx * 4 + 2][d]; bb2.y = tile[tx * 4 + 3][d];
    *(ushort2*)dst = a; *(ushort2*)(dst + 2) = bb2;
  }
}

// =================================================================================
// softmax_pm (round-10 proven): softmax over k=576 per (b,h,q) row, no P write-back.
// =================================================================================
__global__ __launch_bounds__(512) void softmax_pm_kernel(const u16* __restrict__ SP,
                                                         float* __restrict__ attnOut,
                                                         u16* __restrict__ Pm) {
  const int b = blockIdx.x, c = blockIdx.y;
  const int h = threadIdx.x >> 6, l = threadIdx.x & 63;
  __shared__ float pl[8][576];  // 18.4 KB
  float pacc[9] = {};
#pragma unroll 1
  for (int qq = 0; qq < 10; ++qq) {
    const u16* row = SP + ((size_t)((b * 8 + h) * 144 + c * 10 + qq)) * 576;
    float x[9];
#pragma unroll
    for (int i = 0; i < 9; ++i) x[i] = bf2f(row[l + 64 * i]);
    float m = x[0];
#pragma unroll
    for (int i = 1; i < 9; ++i) m = fmaxf(m, x[i]);
#pragma unroll
    for (int o = 32; o >= 1; o >>= 1) m = fmaxf(m, __shfl_xor(m, o));
    float e[9], s = 0.f;
#pragma unroll
    for (int i = 0; i < 9; ++i) { e[i] = expf(x[i] - m); s += e[i]; }
#pragma unroll
    for (int o = 32; o >= 1; o >>= 1) s += __shfl_xor(s, o);
    const float inv = 1.f / s;
#pragma unroll
    for (int i = 0; i < 9; ++i) {
      const float p = e[i] * inv;
      pacc[i] += p;
      pl[h][l + 64 * i] = p;
    }
    __syncthreads();
    float* out = attnOut + ((size_t)(b * 140 + c * 10 + qq)) * 576;
    {
      const int j = threadIdx.x;
      float a = 0.f;
#pragma unroll
      for (int hh = 0; hh < 8; ++hh) a += pl[hh][j];
      out[j] = a * 0.125f;
      if (j < 64) {
        float a2 = 0.f;
#pragma unroll
        for (int hh = 0; hh < 8; ++hh) a2 += pl[hh][j + 512];
        out[j + 512] = a2 * 0.125f;
      }
    }
    __syncthreads();  // pl reused next qq
  }
  u16* pm = Pm + ((size_t)((b * 8 + h) * 14 + c)) * 576;
#pragma unroll
  for (int i = 0; i < 9; ++i) pm[l + 64 * i] = f2bf(pacc[i] * 0.1f);
}

// =================================================================================
// pv_small v2: one head per block, grid (64,8), 256 thr = 4 waves.
// =================================================================================
__global__ __launch_bounds__(256) void pv_small_kernel(const u16* __restrict__ Pm,
                                                       const u16* __restrict__ Vt,
                                                       u16* __restrict__ Attd) {
  const int b = blockIdx.x, h = blockIdx.y;
  const int t = threadIdx.x;
  const int w = t >> 6, l = t & 63;
  const int lr = l & 15, lg = l >> 4;
  __shared__ u16 pm[16][584];  // rows 14,15 + chunk 72 zeroed
  for (int i = t; i < 16 * 73; i += 256) {
    const int r = i / 73, ck = i - (i / 73) * 73;
    uint4 v = {0u, 0u, 0u, 0u};
    if (r < 14 && ck < 72)
      v = *(const uint4*)&Pm[((size_t)((b * 8 + h) * 14 + r)) * 576 + ck * 8];
    *(uint4*)&pm[r][ck * 8] = v;
  }
  __syncthreads();
  const u16* vbase = Vt + ((size_t)(b * 8 + h) * 128) * 576;
  f32x4 acc[2] = {};
#pragma unroll 1
  for (int ks = 0; ks < 18; ++ks) {
    const bf16x8 af = *(const bf16x8*)&pm[lr][ks * 32 + lg * 8];
#pragma unroll
    for (int j = 0; j < 2; ++j) {
      const int nf = w * 2 + j;
      const bf16x8 bf = *(const bf16x8*)&vbase[(size_t)(nf * 16 + lr) * 576 + ks * 32 + lg * 8];
      acc[j] = __builtin_amdgcn_mfma_f32_16x16x32_bf16(af, bf, acc[j], 0, 0, 0);
    }
  }
#pragma unroll
  for (int j = 0; j < 2; ++j) {
    const int nf = w * 2 + j;
#pragma unroll
    for (int rg = 0; rg < 4; ++rg) {
      const int cc = lg * 4 + rg;
      if (cc < 14)
        Attd[((size_t)b * 14 + cc) * 1024 + h * 128 + nf * 16 + lr] = f2bf(acc[j][rg]);
    }
  }
}

// ---------------- LN + per-class linear row ----------------
__global__ __launch_bounds__(256) void ln_crossfc_kernel(
    const float* __restrict__ ap, const float* __restrict__ g, const float* __restrict__ bb,
    const float* __restrict__ fw, const float* __restrict__ fb, float* __restrict__ out) {
  const int bc = blockIdx.x;
  const int c = bc % 14;
  const float* x = ap + (size_t)bc * 1024;
  __shared__ float red[4];
  const int t = threadIdx.x;
  float v[4];
  float s = 0.f;
#pragma unroll
  for (int i = 0; i < 4; ++i) { v[i] = x[t + i * 256]; s += v[i]; }
  const float mean = block_sum(s, red) * (1.f / 1024.f);
  float vs = 0.f;
#pragma unroll
  for (int i = 0; i < 4; ++i) { const float d = v[i] - mean; vs += d * d; }
  const float var = block_sum(vs, red) * (1.f / 1024.f);
  const float inv = rsqrtf(var + 1e-5f);
  float acc = 0.f;
#pragma unroll
  for (int i = 0; i < 4; ++i) {
    const int e = t + i * 256;
    const float h = (v[i] - mean) * inv * g[e] + bb[e];
    acc += h * fw[(size_t)c * 1024 + e];
  }
  acc = block_sum(acc, red);
  if (t == 0) out[bc] = acc + fb[c];
}

// =================================================================================
// direct MLP v3 (round-13 proven): grid (64,4), 256 thr, partials to Lpart.
// =================================================================================
__global__ __launch_bounds__(256) void direct_mlp_kernel(
    const float* __restrict__ vg, const float* __restrict__ g, const float* __restrict__ bb,
    const float* __restrict__ w1, const float* __restrict__ b1,
    const float* __restrict__ w2, float* __restrict__ Lpart) {
  const int b = blockIdx.x, q = blockIdx.y;
  __shared__ float red[4];
  __shared__ float gn[1024];
  __shared__ float h1[128];
  const int t = threadIdx.x;
  const float* x = vg + (size_t)b * 1024;
  float v[4];
  float s = 0.f;
#pragma unroll
  for (int i = 0; i < 4; ++i) { v[i] = x[t + i * 256]; s += v[i]; }
  const float mean = block_sum(s, red) * (1.f / 1024.f);
  float vs = 0.f;
#pragma unroll
  for (int i = 0; i < 4; ++i) { const float d = v[i] - mean; vs += d * d; }
  const float var = block_sum(vs, red) * (1.f / 1024.f);
  const float inv = rsqrtf(var + 1e-5f);
#pragma unroll
  for (int i = 0; i < 4; ++i) {
    const int e = t + i * 256;
    gn[e] = (v[i] - mean) * inv * g[e] + bb[e];
  }
  __syncthreads();
  {
    const int row = q * 128 + (t >> 1);  // 2 threads per row
    const int half = t & 1;
    const float4* wr = (const float4*)(w1 + (size_t)row * 1024 + half * 512);
    const float4* g4 = (const float4*)(gn + half * 512);
    float a = 0.f;
    for (int e = 0; e < 128; ++e) {
      const float4 wv = wr[e], av = g4[e];
      a += av.x * wv.x + av.y * wv.y + av.z * wv.z + av.w * wv.w;
    }
    a += __shfl_xor(a, 1);  // pair lanes (2r, 2r+1)
    if (half == 0) h1[t >> 1] = fmaxf(a + b1[row], 0.f);
  }
  __syncthreads();
  for (int c = 0; c < 14; ++c) {
    float a = 0.f;
    if (t < 128) a = h1[t] * w2[(size_t)c * 512 + q * 128 + t];
    a = block_sum(a, red);
    if (t == 0) Lpart[((size_t)b * 4 + q) * 14 + c] = a;
  }
}

// ---------------- small f32 linear (round-7 proven: 1 row/block, grid (64,4)) ----------------
__global__ __launch_bounds__(256) void linear_f32_kernel(
    const float* __restrict__ A, const float* __restrict__ W, const float* __restrict__ bias,
    float* __restrict__ C, int N, int Kd) {
  const int r = blockIdx.x;
  const int j = blockIdx.y * 256 + threadIdx.x;
  __shared__ float a[1024];
  for (int e = threadIdx.x; e < Kd; e += 256) a[e] = A[(size_t)r * Kd + e];
  __syncthreads();
  float acc = bias ? bias[j] : 0.f;
  const float4* wr = (const float4*)(W + (size_t)j * Kd);
  const float4* a4 = (const float4*)a;
  for (int e = 0; e < Kd / 4; ++e) {
    float4 wv = wr[e], av = a4[e];
    acc += av.x * wv.x + av.y * wv.y + av.z * wv.z + av.w * wv.w;
  }
  C[(size_t)r * N + j] = acc;
}

// ---------------- cosine sim / TEMP + combine (sums MLP partials) ----------------
__global__ __launch_bounds__(256) void sim_combine_kernel(
    const float* __restrict__ co, const float* __restrict__ tp,
    const float* __restrict__ lc, const float* __restrict__ Lpart,
    const float* __restrict__ b2, float* __restrict__ out) {
  const int b = blockIdx.x;
  const int t = threadIdx.x;
  __shared__ float red[4];
  const float* c = co + (size_t)b * 1024;
  const float* p = tp + (size_t)b * 1024;
  float dd = 0.f, nc = 0.f, nt = 0.f;
  for (int e = t; e < 1024; e += 256) {
    const float cv = c[e], pv = p[e];
    dd += cv * pv; nc += cv * cv; nt += pv * pv;
  }
  dd = block_sum(dd, red);
  nc = block_sum(nc, red);
  nt = block_sum(nt, red);
  const float sim = dd / (fmaxf(sqrtf(nc), 1e-12f) * fmaxf(sqrtf(nt), 1e-12f)) / 0.1f;
  if (t < 14) {
    const int i = b * 14 + t;
    const float ld = ((Lpart[((size_t)b * 4 + 0) * 14 + t] +
                       Lpart[((size_t)b * 4 + 1) * 14 + t]) +
                      Lpart[((size_t)b * 4 + 2) * 14 + t]) +
                     Lpart[((size_t)b * 4 + 3) * 14 + t] + b2[t];
    const float sup = 0.5f * (lc[i] + ld);
    out[i] = sim;
    out[896 + i] = sup;
    out[1792 + i] = 0.5f * (sup + sim);
  }
}

// ---------------- workspace layout ----------------
static constexpr size_t OFF_X    = 0;
static constexpr size_t OFF_K    = OFF_X + 75497472;   // Kb; later Pm (8.3MB)
static constexpr size_t OFF_SP   = OFF_K + 75759616;   // V-fallback / S+P
static constexpr size_t OFF_WIN  = OFF_SP + 85082112;
static constexpr size_t OFF_WOUT = OFF_WIN + 6291456;
static constexpr size_t OFF_ASP  = OFF_WOUT + 2097152; // Asp; later Lpart (14KB)
static constexpr size_t OFF_QASP = OFF_ASP + 524288;
static constexpr size_t OFF_ATT  = OFF_QASP + 524288;
static constexpr size_t OFF_APRJ = OFF_ATT + 1835008;
static constexpr size_t OFF_TP   = OFF_APRJ + 3670016;
static constexpr size_t OFF_CV   = OFF_TP + 262144;
static constexpr size_t OFF_CO   = OFF_CV + 262144;
static constexpr size_t OFF_SIM  = OFF_CO + 262144;
static constexpr size_t OFF_LC   = OFF_SIM + 4096;
static constexpr size_t OFF_LD   = OFF_LC + 4096;
static constexpr size_t WS_SMALL = OFF_LD + 4096;
static constexpr size_t OFF_VT   = WS_SMALL;
static constexpr size_t WS_BIG   = OFF_VT + 75497472;

extern "C" void kernel_launch(void* const* d_in, const int* in_sizes, int n_in,
                              void* d_out, int out_size, void* d_ws, size_t ws_size,
                              hipStream_t stream) {
  (void)in_sizes; (void)n_in; (void)out_size;
  const float* vision_features = (const float*)d_in[0];
  const float* text_embeddings = (const float*)d_in[1];
  const float* vision_global   = (const float*)d_in[2];
  const float* aspect_queries  = (const float*)d_in[3];
  const float* ch_in_w  = (const float*)d_in[4];
  const float* ch_in_b  = (const float*)d_in[5];
  const float* ch_out_w = (const float*)d_in[6];
  const float* ch_out_b = (const float*)d_in[7];
  const float* tp_w = (const float*)d_in[8];
  const float* tp_b = (const float*)d_in[9];
  const float* ca_in_w  = (const float*)d_in[10];
  const float* ca_in_b  = (const float*)d_in[11];
  const float* ca_out_w = (const float*)d_in[12];
  const float* ca_out_b = (const float*)d_in[13];
  const float* cross_ln_g = (const float*)d_in[14];
  const float* cross_ln_b = (const float*)d_in[15];
  const float* cross_fc_w = (const float*)d_in[16];
  const float* cross_fc_b = (const float*)d_in[17];
  const float* dir_ln_g = (const float*)d_in[18];
  const float* dir_ln_b = (const float*)d_in[19];
  const float* dir_w1 = (const float*)d_in[20];
  const float* dir_b1 = (const float*)d_in[21];
  const float* dir_w2 = (const float*)d_in[22];
  const float* dir_b2 = (const float*)d_in[23];

  if (ws_size < WS_SMALL) {
    fprintf(stderr, "kernel_launch: ws too small: %zu < %zu\n", ws_size, WS_SMALL);
    return;
  }
  const bool big = (ws_size >= WS_BIG);

  char* ws = (char*)d_ws;
  u16* Xb      = (u16*)(ws + OFF_X);
  u16* Kb      = (u16*)(ws + OFF_K);
  u16* Pm      = (u16*)(ws + OFF_K);   // after S-GEMM, Kb is dead
  u16* Vb      = (u16*)(ws + OFF_SP);
  u16* SP      = (u16*)(ws + OFF_SP);
  u16* Vt      = big ? (u16*)(ws + OFF_VT) : (u16*)(ws + OFF_X);
  u16* Win     = (u16*)(ws + OFF_WIN);
  u16* Wout    = (u16*)(ws + OFF_WOUT);
  u16* Asp     = (u16*)(ws + OFF_ASP);
  float* Lpart = (float*)(ws + OFF_ASP);  // after KVQ, Asp is dead
  u16* Qasp    = (u16*)(ws + OFF_QASP);
  u16* Attd    = (u16*)(ws + OFF_ATT);
  float* Aprj  = (float*)(ws + OFF_APRJ);
  float* Tp    = (float*)(ws + OFF_TP);
  float* Cv2   = (float*)(ws + OFF_CV);
  float* Co    = (float*)(ws + OFF_CO);
  float* Lc    = (float*)(ws + OFF_LC);
  float* attnOut = (float*)d_out + 2688;

  // ---- converts to bf16 ----
  cvt4_kernel<<<3107, 256, 0, stream>>>(vision_features, Xb, ca_in_w, Win,
                                        ca_out_w, Wout, aspect_queries, Asp);

  // ---- fused K+V+Q projections, 256x256 4-phase pipeline ----
  if (big) {
    gemm_kvq_kernel<1><<<dim3(1156), 512, 0, stream>>>(
        Xb, Win + 1024 * 1024, Asp, Win, Kb, nullptr, Vt, Qasp,
        ca_in_b + 1024, ca_in_b);
  } else {
    gemm_kvq_kernel<0><<<dim3(1156), 512, 0, stream>>>(
        Xb, Win + 1024 * 1024, Asp, Win, Kb, Vb, nullptr, Qasp,
        ca_in_b + 1024, ca_in_b);
    transpose_v_kernel<<<dim3(9, 16, 64), 256, 0, stream>>>(Vb, Vt);
  }

  // ---- direct MLP v3 (Asp region now dead; writes Lpart there) ----
  direct_mlp_kernel<<<dim3(64, 4), 256, 0, stream>>>(
      vision_global, dir_ln_g, dir_ln_b, dir_w1, dir_b1, dir_w2, Lpart);

  // ---- S = Q K^T / sqrt(128): KT=2, grid (5 n-tiles, 512 bh), bf16 out ----
  gemm_big_kernel<0><<<dim3(5, 512), 512, 0, stream>>>(
      Qasp, Kb, SP, nullptr, 0.08838834764831845f,
      2, 5, 140, 576, 1024, 1024, 576, 8,
      0L, 128L, 589824L, 128L, 663552L, 82944L);

  // ---- softmax + head-mean attnOut + query-mean Pm ----
  softmax_pm_kernel<<<dim3(64, 14), 512, 0, stream>>>(SP, attnOut, Pm);

  // ---- attended = Pm . V  (pv_small v2) ----
  pv_small_kernel<<<dim3(64, 8), 256, 0, stream>>>(Pm, Vt, Attd);

  // ---- out projection: KT=16, grid (4x8 tiles), f32 out ----
  gemm_big_kernel<1><<<dim3(32, 1), 512, 0, stream>>>(
      Attd, Wout, Aprj, ca_out_b, 1.0f,
      16, 8, 896, 1024, 1024, 1024, 1024, 1,
      0L, 0L, 0L, 0L, 0L, 0L);

  // ---- LN + per-class fc ----
  ln_crossfc_kernel<<<896, 256, 0, stream>>>(Aprj, cross_ln_g, cross_ln_b,
                                             cross_fc_w, cross_fc_b, Lc);

  // ---- contrastive chain (f32; 1-key attention is identity) ----
  linear_f32_kernel<<<dim3(64, 4), 256, 0, stream>>>(text_embeddings, tp_w, tp_b, Tp, 1024, 1024);
  linear_f32_kernel<<<dim3(64, 4), 256, 0, stream>>>(Tp, ch_in_w + 2048 * 1024, ch_in_b + 2048, Cv2, 1024, 1024);
  linear_f32_kernel<<<dim3(64, 4), 256, 0, stream>>>(Cv2, ch_out_w, ch_out_b, Co, 1024, 1024);

  // ---- sim + combine (sums MLP partials + bias) ----
  sim_combine_kernel<<<64, 256, 0, stream>>>(Co, Tp, Lc, Lpart, dir_b2, (float*)d_out);
}